// Round 16
// baseline (715.120 us; speedup 1.0000x reference)
//
#include <hip/hip_runtime.h>
#include <hip/hip_bf16.h>
#include <math.h>

#define D_MODEL   1024
#define VOCAB     50288
#define D_STATE   128
#define D_CONV    4
#define HEADDIM   64
#define CHUNK     64
#define D_INNER   2048
#define NHEADS    32
#define D_IN_PROJ 4384
#define CONV_DIM  2304
#define SEQ       1024
#define NCHUNKS   16
#define EPS       1e-5f
#define SZH       1048576   // SEQ*D_MODEL

typedef __bf16 bf16x8 __attribute__((ext_vector_type(8)));
typedef __bf16 bf16x4 __attribute__((ext_vector_type(4)));
typedef float  f32x4  __attribute__((ext_vector_type(4)));

// ---------------------------------------------------------------- utilities
__device__ __forceinline__ float blockReduceSum256(float v, float* sm) {
    #pragma unroll
    for (int off = 32; off > 0; off >>= 1) v += __shfl_down(v, off);
    if ((threadIdx.x & 63) == 0) sm[threadIdx.x >> 6] = v;
    __syncthreads();
    return sm[0] + sm[1] + sm[2] + sm[3];
}

__device__ __forceinline__ float sigmoidf_(float x) { return 1.0f / (1.0f + expf(-x)); }

__device__ __forceinline__ void gload_lds16(const __bf16* g, __bf16* l) {
    __builtin_amdgcn_global_load_lds(
        (const __attribute__((address_space(1))) void*)g,
        (__attribute__((address_space(3))) void*)l,
        16, 0, 0);
}

// ---------------------------------------------------------------- f32 -> bf16 bulk convert
__global__ void cvt_bf16_k(const float* __restrict__ src, __bf16* __restrict__ dst, long n) {
    long i = ((long)blockIdx.x * 256 + threadIdx.x) * 8;
    long stride = (long)gridDim.x * 256 * 8;
    for (; i < n; i += stride) {
        float4 a = *(const float4*)(src + i);
        float4 b = *(const float4*)(src + i + 4);
        bf16x8 o;
        o[0] = (__bf16)a.x; o[1] = (__bf16)a.y; o[2] = (__bf16)a.z; o[3] = (__bf16)a.w;
        o[4] = (__bf16)b.x; o[5] = (__bf16)b.y; o[6] = (__bf16)b.z; o[7] = (__bf16)b.w;
        *(bf16x8*)(dst + i) = o;
    }
}

// ---------------------------------------------------------------- embedding gather
__global__ void gather_k(const int* __restrict__ ids, const float* __restrict__ emb,
                         float* __restrict__ h) {
    int s = blockIdx.x;
    int id = ids[s];
    const float4* src = (const float4*)(emb + (size_t)id * D_MODEL);
    float4* dst = (float4*)(h + (size_t)s * D_MODEL);
    dst[threadIdx.x] = src[threadIdx.x];
}

// ---------------------------------------------------------------- rmsnorm (tier C)
__global__ void rmsnorm_k(const float* __restrict__ x, const float* __restrict__ w,
                          float* __restrict__ o) {
    __shared__ float red[4];
    int s = blockIdx.x, t = threadIdx.x;
    float4 v = ((const float4*)(x + (size_t)s * D_MODEL))[t];
    float ss = v.x*v.x + v.y*v.y + v.z*v.z + v.w*v.w;
    float tot = blockReduceSum256(ss, red);
    float r = rsqrtf(tot / (float)D_MODEL + EPS);
    float4 wv = ((const float4*)w)[t];
    float4 ov;
    ov.x = v.x * r * wv.x; ov.y = v.y * r * wv.y;
    ov.z = v.z * r * wv.z; ov.w = v.w * r * wv.w;
    ((float4*)(o + (size_t)s * D_MODEL))[t] = ov;
}

// ---------------------------------------------------------------- fold 2 partials + rmsnorm -> bf16
__global__ void rmsnorm_fold_bf16_k(float* __restrict__ h, const float* __restrict__ o,
                                    const float* __restrict__ w, __bf16* __restrict__ out) {
    __shared__ float red[4];
    int s = blockIdx.x, t = threadIdx.x;
    float4 v = ((const float4*)(h + (size_t)s * D_MODEL))[t];
    if (o) {
        #pragma unroll
        for (int j = 0; j < 2; ++j) {
            float4 ov = ((const float4*)(o + (size_t)j * SZH + (size_t)s * D_MODEL))[t];
            v.x += ov.x; v.y += ov.y; v.z += ov.z; v.w += ov.w;
        }
        ((float4*)(h + (size_t)s * D_MODEL))[t] = v;
    }
    float ss = v.x*v.x + v.y*v.y + v.z*v.z + v.w*v.w;
    float tot = blockReduceSum256(ss, red);
    float r = rsqrtf(tot / (float)D_MODEL + EPS);
    float4 wv = ((const float4*)w)[t];
    bf16x4 ov;
    ov[0] = (__bf16)(v.x * r * wv.x); ov[1] = (__bf16)(v.y * r * wv.y);
    ov[2] = (__bf16)(v.z * r * wv.z); ov[3] = (__bf16)(v.w * r * wv.w);
    *(bf16x4*)(out + (size_t)s * D_MODEL + t * 4) = ov;
}

// ---------------------------------------------------------------- gated rmsnorm (tier C)
__global__ void gatednorm_k(float* __restrict__ Y, const float* __restrict__ zx,
                            const float* __restrict__ w) {
    __shared__ float red[4];
    int s = blockIdx.x, t = threadIdx.x;
    float4 y0 = ((const float4*)(Y + (size_t)s * D_INNER))[2*t];
    float4 y1 = ((const float4*)(Y + (size_t)s * D_INNER))[2*t+1];
    float4 z0 = ((const float4*)(zx + (size_t)s * D_IN_PROJ))[2*t];
    float4 z1 = ((const float4*)(zx + (size_t)s * D_IN_PROJ))[2*t+1];
    float g[8];
    float yv[8] = { y0.x,y0.y,y0.z,y0.w, y1.x,y1.y,y1.z,y1.w };
    float zv[8] = { z0.x,z0.y,z0.z,z0.w, z1.x,z1.y,z1.z,z1.w };
    float ss = 0.f;
    #pragma unroll
    for (int j = 0; j < 8; ++j) {
        float gg = yv[j] * zv[j] * sigmoidf_(zv[j]);
        g[j] = gg;
        ss += gg * gg;
    }
    float tot = blockReduceSum256(ss, red);
    float r = rsqrtf(tot / (float)D_INNER + EPS);
    float4 o0, o1;
    o0.x = g[0]*r*w[8*t+0]; o0.y = g[1]*r*w[8*t+1]; o0.z = g[2]*r*w[8*t+2]; o0.w = g[3]*r*w[8*t+3];
    o1.x = g[4]*r*w[8*t+4]; o1.y = g[5]*r*w[8*t+5]; o1.z = g[6]*r*w[8*t+6]; o1.w = g[7]*r*w[8*t+7];
    ((float4*)(Y + (size_t)s * D_INNER))[2*t]   = o0;
    ((float4*)(Y + (size_t)s * D_INNER))[2*t+1] = o1;
}

// ---------------------------------------------------------------- gated rmsnorm -> bf16
__global__ void gatednorm_bf16_k(const float* __restrict__ Y, const float* __restrict__ zx0,
                                 const float* __restrict__ zx1,
                                 const float* __restrict__ w, __bf16* __restrict__ o) {
    __shared__ float red[4];
    int s = blockIdx.x, t = threadIdx.x;
    float4 y0 = ((const float4*)(Y + (size_t)s * D_INNER))[2*t];
    float4 y1 = ((const float4*)(Y + (size_t)s * D_INNER))[2*t+1];
    float4 z0 = ((const float4*)(zx0 + (size_t)s * D_IN_PROJ))[2*t];
    float4 z1 = ((const float4*)(zx0 + (size_t)s * D_IN_PROJ))[2*t+1];
    if (zx1) {
        float4 a0 = ((const float4*)(zx1 + (size_t)s * D_IN_PROJ))[2*t];
        float4 a1 = ((const float4*)(zx1 + (size_t)s * D_IN_PROJ))[2*t+1];
        z0.x += a0.x; z0.y += a0.y; z0.z += a0.z; z0.w += a0.w;
        z1.x += a1.x; z1.y += a1.y; z1.z += a1.z; z1.w += a1.w;
    }
    float g[8];
    float yv[8] = { y0.x,y0.y,y0.z,y0.w, y1.x,y1.y,y1.z,y1.w };
    float zv[8] = { z0.x,z0.y,z0.z,z0.w, z1.x,z1.y,z1.z,z1.w };
    float ss = 0.f;
    #pragma unroll
    for (int j = 0; j < 8; ++j) {
        float gg = yv[j] * zv[j] * sigmoidf_(zv[j]);
        g[j] = gg;
        ss += gg * gg;
    }
    float tot = blockReduceSum256(ss, red);
    float r = rsqrtf(tot / (float)D_INNER + EPS);
    bf16x8 ov;
    #pragma unroll
    for (int j = 0; j < 8; ++j) ov[j] = (__bf16)(g[j] * r * w[8*t+j]);
    *(bf16x8*)(o + (size_t)s * D_INNER + t * 8) = ov;
}

// ---------------------------------------------------------------- 256x128 deep-interleaved GEMM (BT), 3-buffer ring (r14 best):
// BK=32, 3x24KB LDS (72KB -> 2 blocks/CU), prefetch 2 ahead, 2 phases/iter
// {stage || ds_read || 8 MFMA}, FIFO vmcnt(5/3/0), 2-way-free swizzle, setprio, XCD remap.
__global__ __launch_bounds__(512) void gemm256n128_d3(const __bf16* __restrict__ A,
                                                      const __bf16* __restrict__ B,
                                                      float* __restrict__ C,
                                                      int N, int K,
                                                      int lda, int ldb, int ldc,
                                                      int ntiles) {
    __shared__ __bf16 lds[3 * 12288];   // buf: A[256][32] @0 (8192 el), B[128][32] @8192 (4096 el)

    const int d = blockIdx.x;
    const int xcd = d & 7, kk = d >> 3;
    const int m_tile = kk & 3, p = kk >> 2;        // 4 M-tiles (M=1024)
    const int n_tile = xcd + (p << 3);
    if (n_tile >= ntiles) return;
    const int bm0 = m_tile * 256, bn0 = n_tile * 128;

    const int tid = threadIdx.x;
    const int l = tid & 63, w = tid >> 6;
    const int wr = w >> 2, wc = w & 3;             // 2x4 wave grid; wave owns 128x32
    const int lrow = l & 15;
    const int khi = l >> 4;
    const int kb = ((khi ^ ((lrow >> 1) & 3)) << 3);
    const int Lr = l >> 2;                          // row within 16-row chunk
    const int sblk = (((l & 3) ^ ((Lr >> 1) & 3)) << 3);

    int aoff[8], boff[2];
    #pragma unroll
    for (int m = 0; m < 8; ++m) aoff[m] = (wr * 128 + m * 16 + lrow) * 32;
    #pragma unroll
    for (int n = 0; n < 2; ++n) boff[n] = 8192 + (wc * 32 + n * 16 + lrow) * 32;

    f32x4 acc[8][2];
    #pragma unroll
    for (int m = 0; m < 8; ++m)
        #pragma unroll
        for (int n = 0; n < 2; ++n) acc[m][n] = (f32x4){0.f,0.f,0.f,0.f};

    auto stage_a = [&](int kt, __bf16* dst) {
        #pragma unroll
        for (int r = 0; r < 2; ++r) {
            int chunk = r * 8 + w;
            int grow = bm0 + chunk * 16 + Lr;
            const __bf16* g = A + (size_t)grow * lda + kt * 32 + sblk;
            gload_lds16(g, dst + chunk * 512);
        }
    };
    auto stage_b = [&](int kt, __bf16* dst) {
        int grow = bn0 + w * 16 + Lr;
        if (grow > N - 1) grow = N - 1;
        const __bf16* g = B + (size_t)grow * ldb + kt * 32 + sblk;
        gload_lds16(g, dst + w * 512);
    };

    // prologue: tiles 0,1 in flight (6 loads/thread)
    stage_a(0, lds);          stage_b(0, lds + 8192);
    stage_a(1, lds + 12288);  stage_b(1, lds + 12288 + 8192);

    const int nt = K / 32;   // 32
    for (int t = 0; t < nt; ++t) {
        __bf16* bb = lds + (t % 3) * 12288;
        __bf16* nb = lds + ((t + 2) % 3) * 12288;
        bf16x8 af[4], bfv[2];

        if (t + 2 < nt) {
            stage_a(t + 2, nb);
            asm volatile("s_waitcnt vmcnt(5)" ::: "memory");  // t+1(3) + A(t+2)(2) remain
        } else if (t + 1 < nt) {
            asm volatile("s_waitcnt vmcnt(3)" ::: "memory");
        } else {
            asm volatile("s_waitcnt vmcnt(0)" ::: "memory");
        }
        __builtin_amdgcn_s_barrier();
        #pragma unroll
        for (int m = 0; m < 4; ++m) af[m] = *(const bf16x8*)&bb[aoff[m] + kb];
        #pragma unroll
        for (int n = 0; n < 2; ++n) bfv[n] = *(const bf16x8*)&bb[boff[n] + kb];
        __builtin_amdgcn_s_setprio(1);
        #pragma unroll
        for (int m = 0; m < 4; ++m)
            #pragma unroll
            for (int n = 0; n < 2; ++n)
                acc[m][n] = __builtin_amdgcn_mfma_f32_16x16x32_bf16(af[m], bfv[n], acc[m][n], 0, 0, 0);
        __builtin_amdgcn_s_setprio(0);
        __builtin_amdgcn_s_barrier();

        if (t + 2 < nt) stage_b(t + 2, nb + 8192);
        #pragma unroll
        for (int m = 0; m < 4; ++m) af[m] = *(const bf16x8*)&bb[aoff[m + 4] + kb];
        __builtin_amdgcn_s_setprio(1);
        #pragma unroll
        for (int m = 0; m < 4; ++m)
            #pragma unroll
            for (int n = 0; n < 2; ++n)
                acc[m + 4][n] = __builtin_amdgcn_mfma_f32_16x16x32_bf16(af[m], bfv[n], acc[m + 4][n], 0, 0, 0);
        __builtin_amdgcn_s_setprio(0);
        __builtin_amdgcn_s_barrier();
    }

    // epilogue: C/D layout col = l&15, row = (l>>4)*4 + reg
    const int r0q = (l >> 4) * 4;
    #pragma unroll
    for (int m = 0; m < 8; ++m) {
        int gr = bm0 + wr * 128 + m * 16 + r0q;
        #pragma unroll
        for (int n = 0; n < 2; ++n) {
            int gc = bn0 + wc * 32 + n * 16 + lrow;
            if (gc < N) {
                #pragma unroll
                for (int rr = 0; rr < 4; ++rr)
                    C[(size_t)(gr + rr) * ldc + gc] = acc[m][n][rr];
            }
        }
    }
}

// ---------------------------------------------------------------- bf16 MFMA GEMM (BT), XCD-affinity + split-K (in/out_proj)
template<int TM, int TN, int MTL2, bool ACC>
__global__ __launch_bounds__(256) void gemm_bt_bf16(const __bf16* __restrict__ A,
                                                    const __bf16* __restrict__ B,
                                                    float* __restrict__ C,
                                                    int N, int klen,
                                                    int lda, int ldb, int ldc,
                                                    int ntiles, size_t csplit) {
    constexpr int FM = TM / 32;
    constexpr int FN = TN / 32;
    __shared__ __bf16 As[TM * 32];
    __shared__ __bf16 Bs[TN * 32];

    const int d = blockIdx.x;
    const int xcd = d & 7;
    const int kk = d >> 3;
    const int p = kk >> MTL2;
    const int m_tile = kk & ((1 << MTL2) - 1);
    const int n_tile = xcd + (p << 3);
    if (n_tile >= ntiles) return;

    const int k_begin = blockIdx.y * klen;
    C += (size_t)blockIdx.y * csplit;

    const int bm0 = m_tile * TM;
    const int bn0 = n_tile * TN;
    const int t = threadIdx.x;
    const int l = t & 63;
    const int w = t >> 6;
    const int wr = w >> 1, wc = w & 1;
    const int lrow = l & 15;
    const int lk   = (l >> 4) * 8;
    const int srow = l >> 2;
    const int scol = (l & 3) * 8;

    f32x4 acc[FM][FN];
    #pragma unroll
    for (int m = 0; m < FM; ++m)
        #pragma unroll
        for (int n = 0; n < FN; ++n)
            acc[m][n] = (f32x4){0.f, 0.f, 0.f, 0.f};

    for (int k0 = k_begin; k0 < k_begin + klen; k0 += 32) {
        __syncthreads();
        #pragma unroll
        for (int i = 0; i < TM / 64; ++i) {
            int r0 = w * (TM / 4) + i * 16;
            const __bf16* g = A + (size_t)(bm0 + r0 + srow) * lda + k0 + scol;
            gload_lds16(g, As + (size_t)r0 * 32);
        }
        #pragma unroll
        for (int i = 0; i < TN / 64; ++i) {
            int r0 = w * (TN / 4) + i * 16;
            int gn = bn0 + r0 + srow; if (gn > N - 1) gn = N - 1;
            const __bf16* g = B + (size_t)gn * ldb + k0 + scol;
            gload_lds16(g, Bs + (size_t)r0 * 32);
        }
        __syncthreads();

        bf16x8 af[FM], bfr[FN];
        #pragma unroll
        for (int m = 0; m < FM; ++m)
            af[m] = *(const bf16x8*)&As[(wr * (TM/2) + m * 16 + lrow) * 32 + lk];
        #pragma unroll
        for (int n = 0; n < FN; ++n)
            bfr[n] = *(const bf16x8*)&Bs[(wc * (TN/2) + n * 16 + lrow) * 32 + lk];
        #pragma unroll
        for (int m = 0; m < FM; ++m)
            #pragma unroll
            for (int n = 0; n < FN; ++n)
                acc[m][n] = __builtin_amdgcn_mfma_f32_16x16x32_bf16(af[m], bfr[n], acc[m][n], 0, 0, 0);
    }

    const int r0 = (l >> 4) * 4;
    #pragma unroll
    for (int m = 0; m < FM; ++m) {
        #pragma unroll
        for (int rr = 0; rr < 4; ++rr) {
            int gr = bm0 + wr * (TM/2) + m * 16 + r0 + rr;
            #pragma unroll
            for (int n = 0; n < FN; ++n) {
                int gc = bn0 + wc * (TN/2) + n * 16 + lrow;
                if (gc < N) {
                    size_t off = (size_t)gr * ldc + gc;
                    if (ACC) C[off] += acc[m][n][rr];
                    else     C[off]  = acc[m][n][rr];
                }
            }
        }
    }
}

// ---------------------------------------------------------------- f32-input cvt GEMM (fallback tier)
template<bool ACC>
__global__ __launch_bounds__(256) void gemm_nt_cvt(const float* __restrict__ A,
                                                   const float* __restrict__ B,
                                                   float* __restrict__ C,
                                                   int M, int N, int K,
                                                   int lda, int ldb, int ldc) {
    __shared__ __bf16 As[128][40];
    __shared__ __bf16 Bs[128][40];
    const int bm0 = blockIdx.x * 128;
    const int bn0 = blockIdx.y * 128;
    const int t = threadIdx.x;
    const int l = t & 63;
    const int w = t >> 6;
    const int wr = w >> 1;
    const int wc = w & 1;
    const int lrow = l & 15;
    const int lk   = (l >> 4) * 8;

    f32x4 acc[4][4];
    #pragma unroll
    for (int m = 0; m < 4; ++m)
        #pragma unroll
        for (int n = 0; n < 4; ++n)
            acc[m][n] = (f32x4){0.f, 0.f, 0.f, 0.f};

    for (int k0 = 0; k0 < K; k0 += 32) {
        __syncthreads();
        float4 av[4], bv[4];
        #pragma unroll
        for (int i = 0; i < 4; ++i) {
            int idx = t + i * 256;
            int r = idx >> 3;
            int c4 = (idx & 7) * 4;
            av[i] = *(const float4*)(A + (size_t)(bm0 + r) * lda + k0 + c4);
            int gn = bn0 + r; if (gn > N - 1) gn = N - 1;
            bv[i] = *(const float4*)(B + (size_t)gn * ldb + k0 + c4);
        }
        #pragma unroll
        for (int i = 0; i < 4; ++i) {
            int idx = t + i * 256;
            int r = idx >> 3;
            int c4 = (idx & 7) * 4;
            bf16x4 aw, bw;
            aw[0] = (__bf16)av[i].x; aw[1] = (__bf16)av[i].y;
            aw[2] = (__bf16)av[i].z; aw[3] = (__bf16)av[i].w;
            bw[0] = (__bf16)bv[i].x; bw[1] = (__bf16)bv[i].y;
            bw[2] = (__bf16)bv[i].z; bw[3] = (__bf16)bv[i].w;
            *(bf16x4*)&As[r][c4] = aw;
            *(bf16x4*)&Bs[r][c4] = bw;
        }
        __syncthreads();

        bf16x8 af[4], bfr[4];
        #pragma unroll
        for (int m = 0; m < 4; ++m)
            af[m] = *(const bf16x8*)&As[wr * 64 + m * 16 + lrow][lk];
        #pragma unroll
        for (int n = 0; n < 4; ++n)
            bfr[n] = *(const bf16x8*)&Bs[wc * 64 + n * 16 + lrow][lk];
        #pragma unroll
        for (int m = 0; m < 4; ++m)
            #pragma unroll
            for (int n = 0; n < 4; ++n)
                acc[m][n] = __builtin_amdgcn_mfma_f32_16x16x32_bf16(af[m], bfr[n], acc[m][n], 0, 0, 0);
    }

    const int r0 = (l >> 4) * 4;
    #pragma unroll
    for (int m = 0; m < 4; ++m) {
        #pragma unroll
        for (int rr = 0; rr < 4; ++rr) {
            int gr = bm0 + wr * 64 + m * 16 + r0 + rr;
            #pragma unroll
            for (int n = 0; n < 4; ++n) {
                int gc = bn0 + wc * 64 + n * 16 + lrow;
                if (gc < N) {
                    size_t off = (size_t)gr * ldc + gc;
                    if (ACC) C[off] += acc[m][n][rr];
                    else     C[off]  = acc[m][n][rr];
                }
            }
        }
    }
}

// ---------------------------------------------------------------- causal depthwise conv + silu
__global__ void conv_silu_k(const float* __restrict__ zx0, const float* __restrict__ zx1,
                            const float* __restrict__ w,
                            const float* __restrict__ b, float* __restrict__ xBC) {
    int idx = blockIdx.x * 256 + threadIdx.x;
    if (idx >= SEQ * CONV_DIM) return;
    int s = idx / CONV_DIM, c = idx - s * CONV_DIM;
    float acc = b[c];
    #pragma unroll
    for (int k = 0; k < D_CONV; ++k) {
        int si = s + k - (D_CONV - 1);
        if (si >= 0) {
            size_t o = (size_t)si * D_IN_PROJ + D_INNER + c;
            float v = zx0[o];
            if (zx1) v += zx1[o];
            acc = fmaf(v, w[c * D_CONV + k], acc);
        }
    }
    xBC[idx] = acc * sigmoidf_(acc);
}

// ---------------------------------------------------------------- fused dt=softplus + per-chunk cumsum
__global__ void dtcum_k(const float* __restrict__ zx0, const float* __restrict__ zx1,
                        const float* __restrict__ dt_bias,
                        const float* __restrict__ A_log,
                        float* __restrict__ dtb, float* __restrict__ acs) {
    int c = blockIdx.x, h = blockIdx.y, l = threadIdx.x; // 64 threads
    int s = c * 64 + l;
    size_t o = (size_t)s * D_IN_PROJ + (D_IN_PROJ - NHEADS) + h;
    float v = zx0[o];
    if (zx1) v += zx1[o];
    v += dt_bias[h];
    float dt = (v > 20.f) ? v : log1pf(expf(v));
    dtb[(size_t)s * NHEADS + h] = dt;
    float a = -expf(A_log[h]);
    float x = a * dt;
    #pragma unroll
    for (int off = 1; off < 64; off <<= 1) {
        float oo = __shfl_up(x, off);
        if (l >= off) x += oo;
    }
    acs[(size_t)h * SEQ + s] = x;
}

// ---------------------------------------------------------------- MFMA: CM[c] = C·B^T + Btg (B transposed, bf16)
__global__ __launch_bounds__(256) void cmg_k(const float* __restrict__ xBC,
                                             float* __restrict__ cm,
                                             __bf16* __restrict__ btg) {
    const int c = blockIdx.x;
    const int LDP = 136;
    __shared__ __bf16 Cs[64 * 136];
    __shared__ __bf16 Bs[64 * 136];
    const int t = threadIdx.x;
    const int l = t & 63;
    const int w = t >> 6;

    #pragma unroll
    for (int i = 0; i < 8; ++i) {
        int e = t + i * 256;
        int row = e >> 5, n4 = (e & 31) * 4;
        float4 vc = *(const float4*)(xBC + (size_t)(c*64 + row) * CONV_DIM + D_INNER + D_STATE + n4);
        float4 vb = *(const float4*)(xBC + (size_t)(c*64 + row) * CONV_DIM + D_INNER + n4);
        bf16x4 cc, bb;
        cc[0] = (__bf16)vc.x; cc[1] = (__bf16)vc.y; cc[2] = (__bf16)vc.z; cc[3] = (__bf16)vc.w;
        bb[0] = (__bf16)vb.x; bb[1] = (__bf16)vb.y; bb[2] = (__bf16)vb.z; bb[3] = (__bf16)vb.w;
        *(bf16x4*)&Cs[row * LDP + n4] = cc;
        *(bf16x4*)&Bs[row * LDP + n4] = bb;
    }
    __syncthreads();

    #pragma unroll
    for (int i = 0; i < 4; ++i) {
        int e8 = t + i * 256;
        int n = e8 >> 3, l8 = (e8 & 7) * 8;
        bf16x8 o;
        #pragma unroll
        for (int j = 0; j < 8; ++j) o[j] = Bs[(l8 + j) * LDP + n];
        *(bf16x8*)(btg + ((size_t)c * 128 + n) * 64 + l8) = o;
    }

    const int lrow = l & 15;
    const int lk   = (l >> 4) * 8;
    const int l0 = w * 16;
    f32x4 acc[4];
    #pragma unroll
    for (int n = 0; n < 4; ++n) acc[n] = (f32x4){0.f,0.f,0.f,0.f};
    #pragma unroll
    for (int kc = 0; kc < 4; ++kc) {
        bf16x8 a = *(const bf16x8*)&Cs[(l0 + lrow) * LDP + kc * 32 + lk];
        #pragma unroll
        for (int n = 0; n < 4; ++n) {
            bf16x8 b = *(const bf16x8*)&Bs[(n * 16 + lrow) * LDP + kc * 32 + lk];
            acc[n] = __builtin_amdgcn_mfma_f32_16x16x32_bf16(a, b, acc[n], 0, 0, 0);
        }
    }
    const int r0 = (l >> 4) * 4;
    #pragma unroll
    for (int n = 0; n < 4; ++n)
        #pragma unroll
        for (int r = 0; r < 4; ++r)
            cm[(size_t)c * 4096 + (l0 + r0 + r) * 64 + n * 16 + lrow] = acc[n][r];
}

// ---------------------------------------------------------------- MFMA fused Y_diag + states, per (c,h)
__global__ __launch_bounds__(256) void ydst_k(const float* __restrict__ cm,
                                              const __bf16* __restrict__ btg,
                                              const float* __restrict__ xBC,
                                              const float* __restrict__ dtb,
                                              const float* __restrict__ acs,
                                              float* __restrict__ Y,
                                              float* __restrict__ st) {
    const int c = blockIdx.x, h = blockIdx.y;
    const int LDP = 72;
    __shared__ __bf16 Xt[64 * 72];
    __shared__ __bf16 X2[64 * 72];
    __shared__ __bf16 G [64 * 72];
    __shared__ __bf16 Bt[128 * 72];
    __shared__ float arow[64];
    __shared__ float decl[64];
    const int t = threadIdx.x;
    const int l = t & 63;
    const int w = t >> 6;

    if (t < 64) arow[t] = acs[(size_t)h * SEQ + c * 64 + t];
    __syncthreads();
    const float alast = arow[63];
    if (t < 64) decl[t] = expf(alast - arow[t]);
    #pragma unroll
    for (int i = 0; i < 16; ++i) {
        int e = t + i * 256;
        int gl = e >> 6, sx = e & 63;
        G[gl * LDP + sx] = (sx <= gl) ? (__bf16)(cm[(size_t)c * 4096 + e] * expf(arow[gl] - arow[sx])) : (__bf16)0.f;
    }
    #pragma unroll
    for (int i = 0; i < 4; ++i) {
        int e8 = t + i * 256;
        int n = e8 >> 3, l8 = (e8 & 7) * 8;
        *(bf16x8*)&Bt[n * LDP + l8] = *(const bf16x8*)(btg + ((size_t)c * 128 + n) * 64 + l8);
    }
    __syncthreads();
    #pragma unroll
    for (int i = 0; i < 4; ++i) {
        int e4 = t + i * 256;
        int sx = e4 >> 4, p4 = (e4 & 15) * 4;
        int s = c * 64 + sx;
        float4 v = *(const float4*)(xBC + (size_t)s * CONV_DIM + h * HEADDIM + p4);
        float d = dtb[(size_t)s * NHEADS + h];
        float d2 = d * decl[sx];
        Xt[(p4+0) * LDP + sx] = (__bf16)(v.x * d);
        Xt[(p4+1) * LDP + sx] = (__bf16)(v.y * d);
        Xt[(p4+2) * LDP + sx] = (__bf16)(v.z * d);
        Xt[(p4+3) * LDP + sx] = (__bf16)(v.w * d);
        X2[(p4+0) * LDP + sx] = (__bf16)(v.x * d2);
        X2[(p4+1) * LDP + sx] = (__bf16)(v.y * d2);
        X2[(p4+2) * LDP + sx] = (__bf16)(v.z * d2);
        X2[(p4+3) * LDP + sx] = (__bf16)(v.w * d2);
    }
    __syncthreads();

    const int lrow = l & 15;
    const int lk   = (l >> 4) * 8;
    const int p0 = w * 16;
    const int r0 = (l >> 4) * 4;

    f32x4 acc1[4];
    #pragma unroll
    for (int n = 0; n < 4; ++n) acc1[n] = (f32x4){0.f,0.f,0.f,0.f};
    #pragma unroll
    for (int kc = 0; kc < 2; ++kc) {
        bf16x8 a = *(const bf16x8*)&Xt[(p0 + lrow) * LDP + kc * 32 + lk];
        #pragma unroll
        for (int n = 0; n < 4; ++n) {
            bf16x8 b = *(const bf16x8*)&G[(n * 16 + lrow) * LDP + kc * 32 + lk];
            acc1[n] = __builtin_amdgcn_mfma_f32_16x16x32_bf16(a, b, acc1[n], 0, 0, 0);
        }
    }
    #pragma unroll
    for (int n = 0; n < 4; ++n) {
        int lc = n * 16 + lrow;
        float4 ov; ov.x = acc1[n][0]; ov.y = acc1[n][1]; ov.z = acc1[n][2]; ov.w = acc1[n][3];
        *(float4*)(Y + (size_t)(c*64 + lc) * D_INNER + h * HEADDIM + p0 + r0) = ov;
    }

    f32x4 acc2[8];
    #pragma unroll
    for (int n = 0; n < 8; ++n) acc2[n] = (f32x4){0.f,0.f,0.f,0.f};
    #pragma unroll
    for (int kc = 0; kc < 2; ++kc) {
        bf16x8 a = *(const bf16x8*)&X2[(p0 + lrow) * LDP + kc * 32 + lk];
        #pragma unroll
        for (int n = 0; n < 8; ++n) {
            bf16x8 b = *(const bf16x8*)&Bt[(n * 16 + lrow) * LDP + kc * 32 + lk];
            acc2[n] = __builtin_amdgcn_mfma_f32_16x16x32_bf16(a, b, acc2[n], 0, 0, 0);
        }
    }
    float* stb = st + ((size_t)(c * NHEADS + h) * 64) * 128;
    #pragma unroll
    for (int n = 0; n < 8; ++n) {
        int nc = n * 16 + lrow;
        #pragma unroll
        for (int r = 0; r < 4; ++r)
            stb[(size_t)(p0 + r0 + r) * 128 + nc] = acc2[n][r];
    }
}

// ---------------------------------------------------------------- inter-chunk recurrence
__global__ void rec_k(float* __restrict__ st, const float* __restrict__ acs) {
    int idx = blockIdx.x * 256 + threadIdx.x;
    int h = idx >> 13;
    float S = 0.f;
    for (int c = 0; c < NCHUNKS; ++c) {
        float* p = st + (size_t)c * (NHEADS * D_STATE * HEADDIM) + idx;
        float tmp = *p;
        *p = S;
        float dec = expf(acs[(size_t)h * SEQ + c * 64 + 63]);
        S = fmaf(S, dec, tmp);
    }
}

// ---------------------------------------------------------------- MFMA Y_off + D skip (RMW), per (c,h)
__global__ __launch_bounds__(256) void yoff_k(const float* __restrict__ xBC,
                                              const float* __restrict__ acs,
                                              const float* __restrict__ st,
                                              const float* __restrict__ Dp,
                                              float* __restrict__ Y) {
    const int c = blockIdx.x, h = blockIdx.y;
    const int LDP = 136;
    __shared__ __bf16 Sts[64 * 136];
    __shared__ __bf16 Cs [64 * 136];
    __shared__ float arow[64];
    const int t = threadIdx.x;
    const int l = t & 63;
    const int w = t >> 6;

    if (t < 64) arow[t] = acs[(size_t)h * SEQ + c * 64 + t];
    const float* stb = st + ((size_t)(c * NHEADS + h) * 64) * 128;
    #pragma unroll
    for (int i = 0; i < 8; ++i) {
        int e = t + i * 256;
        int row = e >> 5, n4 = (e & 31) * 4;
        float4 vs = *(const float4*)(stb + (size_t)row * 128 + n4);
        float4 vc = *(const float4*)(xBC + (size_t)(c*64 + row) * CONV_DIM + D_INNER + D_STATE + n4);
        bf16x4 ss, cc;
        ss[0] = (__bf16)vs.x; ss[1] = (__bf16)vs.y; ss[2] = (__bf16)vs.z; ss[3] = (__bf16)vs.w;
        cc[0] = (__bf16)vc.x; cc[1] = (__bf16)vc.y; cc[2] = (__bf16)vc.z; cc[3] = (__bf16)vc.w;
        *(bf16x4*)&Sts[row * LDP + n4] = ss;
        *(bf16x4*)&Cs [row * LDP + n4] = cc;
    }
    __syncthreads();

    const int lrow = l & 15;
    const int lk   = (l >> 4) * 8;
    const int p0 = w * 16;
    const int r0 = (l >> 4) * 4;
    const float dpar = Dp[h];

    f32x4 acc[4];
    #pragma unroll
    for (int n = 0; n < 4; ++n) acc[n] = (f32x4){0.f,0.f,0.f,0.f};
    #pragma unroll
    for (int kc = 0; kc < 4; ++kc) {
        bf16x8 a = *(const bf16x8*)&Sts[(p0 + lrow) * LDP + kc * 32 + lk];
        #pragma unroll
        for (int n = 0; n < 4; ++n) {
            bf16x8 b = *(const bf16x8*)&Cs[(n * 16 + lrow) * LDP + kc * 32 + lk];
            acc[n] = __builtin_amdgcn_mfma_f32_16x16x32_bf16(a, b, acc[n], 0, 0, 0);
        }
    }
    #pragma unroll
    for (int n = 0; n < 4; ++n) {
        int lc = n * 16 + lrow;
        int s = c * 64 + lc;
        float sc = expf(arow[lc]);
        float4 xv = *(const float4*)(xBC + (size_t)s * CONV_DIM + h * HEADDIM + p0 + r0);
        float4 yv = *(float4*)(Y + (size_t)s * D_INNER + h * HEADDIM + p0 + r0);
        yv.x += sc * acc[n][0] + dpar * xv.x;
        yv.y += sc * acc[n][1] + dpar * xv.y;
        yv.z += sc * acc[n][2] + dpar * xv.z;
        yv.w += sc * acc[n][3] + dpar * xv.w;
        *(float4*)(Y + (size_t)s * D_INNER + h * HEADDIM + p0 + r0) = yv;
    }
}

// ---------------------------------------------------------------- host launch
extern "C" void kernel_launch(void* const* d_in, const int* in_sizes, int n_in,
                              void* d_out, int out_size, void* d_ws, size_t ws_size,
                              hipStream_t stream) {
    const int*   ids          = (const int*)d_in[0];
    const float* emb          = (const float*)d_in[1];
    const float* norm_w       = (const float*)d_in[2];
    const float* in_proj_w    = (const float*)d_in[3];
    const float* conv_w       = (const float*)d_in[4];
    const float* conv_b       = (const float*)d_in[5];
    const float* dt_bias      = (const float*)d_in[6];
    const float* A_log        = (const float*)d_in[7];
    const float* Dp           = (const float*)d_in[8];
    const float* mixer_norm_w = (const float*)d_in[9];
    const float* out_proj_w   = (const float*)d_in[10];
    const float* norm_f_w     = (const float*)d_in[11];
    float* out = (float*)d_out;

    const size_t SZ_H = SZH, SZ_U = SZH, SZ_ZX = 4489216, SZ_XBC = 2359296,
                 SZ_DT = 32768, SZ_ACS = 32768, SZ_CM = 65536, SZ_ST = 4194304, SZ_Y = 2097152;
    const size_t SZ_BTG_F = 65536;
    const size_t BF_U = SZ_H, BF_Y = SZ_Y;
    const size_t BF_WIN  = 4ull * 4489216;
    const size_t BF_WOUT = 4ull * 2097152;
    const size_t BF_EMB  = (size_t)VOCAB * D_MODEL;

    const size_t f32_base = SZ_H + SZ_U + SZ_ZX + SZ_XBC + SZ_DT + SZ_ACS + SZ_CM + SZ_BTG_F + SZ_ST + SZ_Y;
    const size_t f32_new  = f32_base + SZ_ZX + 2 * SZ_H;   // zxb + o[2]
    const size_t bf_all   = (BF_U + BF_Y + BF_WIN + BF_WOUT + BF_EMB) * 2;
    const size_t bytesNew = f32_new * 4 + bf_all;
    const size_t bytesOld = f32_base * 4 + bf_all;
    const int tier = (ws_size >= bytesNew) ? 0 : (ws_size >= bytesOld) ? 1 : 2;

    float *h, *u, *dtb, *acs, *cm, *zx, *zxb = nullptr, *xBC, *st, *Y, *o = nullptr;
    __bf16 *btg, *ub = nullptr, *Yb = nullptr, *win = nullptr, *wout = nullptr, *embb = nullptr;

    if (tier <= 1) {
        float* f = (float*)d_ws;
        h = f;   f += SZ_H;
        u = f;   f += SZ_U;
        dtb = f; f += SZ_DT;
        acs = f; f += SZ_ACS;
        cm = f;  f += SZ_CM;
        btg = (__bf16*)f; f += SZ_BTG_F;
        zx = f;  f += SZ_ZX;
        if (tier == 0) {
            zxb = f; f += SZ_ZX;
            o = f;   f += 2 * SZ_H;
        }
        xBC = f; f += SZ_XBC;
        st = f;  f += SZ_ST;
        Y = f;   f += SZ_Y;
        __bf16* bb = (__bf16*)f;
        ub = bb;   bb += BF_U;
        Yb = bb;   bb += BF_Y;
        win = bb;  bb += BF_WIN;
        wout = bb; bb += BF_WOUT;
        embb = bb;
    } else {
        float* f = (float*)d_ws;
        h = f;   f += SZ_H;
        u = f;   f += SZ_U;
        dtb = f; f += SZ_DT;
        acs = f; f += SZ_ACS;
        cm = f;  f += SZ_CM;
        btg = (__bf16*)f; f += SZ_BTG_F;
        float* ob = (float*)d_out;
        zx = ob;
        xBC = zx + SZ_ZX;
        st = xBC + SZ_XBC;
        Y = st + SZ_ST;
    }

    if (tier <= 1) {
        cvt_bf16_k<<<(int)(BF_WIN / 2048), 256, 0, stream>>>(in_proj_w, win, (long)BF_WIN);
        cvt_bf16_k<<<(int)(BF_WOUT / 2048), 256, 0, stream>>>(out_proj_w, wout, (long)BF_WOUT);
        cvt_bf16_k<<<(int)(BF_EMB / 2048), 256, 0, stream>>>(emb, embb, (long)BF_EMB);
    }

    gather_k<<<SEQ, 256, 0, stream>>>(ids, emb, h);

    const int NT_IN  = (D_IN_PROJ + 127) / 128;   // 35
    const int NT_OUT = D_MODEL / 128;             // 8
    const int GX_IN  = 8 * ((NT_IN  + 7) / 8) * 8;   // 320
    const int GX_OUT = 8 * ((NT_OUT + 7) / 8) * 16;  // 128
    const int NT_LM128 = (VOCAB + 127) / 128;     // 393
    const int GX_LM128 = 8 * ((NT_LM128 + 7) / 8) * 4;  // 1600

    for (int l = 0; l < 4; ++l) {
        if (tier <= 1) {
            rmsnorm_fold_bf16_k<<<SEQ, 256, 0, stream>>>(
                h, (tier == 0 && l > 0) ? o : nullptr, norm_w + (size_t)l * D_MODEL, ub);
            if (tier == 0) {
                gemm_bt_bf16<128, 128, 3, false><<<dim3(GX_IN, 2), 256, 0, stream>>>(
                    ub, win + (size_t)l * 4489216, zx,
                    D_IN_PROJ, 512, D_MODEL, D_MODEL, D_IN_PROJ, NT_IN, SZ_ZX);
            } else {
                gemm_bt_bf16<128, 128, 3, false><<<dim3(GX_IN, 1), 256, 0, stream>>>(
                    ub, win + (size_t)l * 4489216, zx,
                    D_IN_PROJ, 1024, D_MODEL, D_MODEL, D_IN_PROJ, NT_IN, 0);
            }
        } else {
            rmsnorm_k<<<SEQ, 256, 0, stream>>>(h, norm_w + (size_t)l * D_MODEL, u);
            gemm_nt_cvt<false><<<dim3(8, 35), 256, 0, stream>>>(
                u, in_proj_w + (size_t)l * D_IN_PROJ * D_MODEL, zx,
                SEQ, D_IN_PROJ, D_MODEL, D_MODEL, D_MODEL, D_IN_PROJ);
        }

        float* zx1 = (tier == 0) ? zxb : nullptr;

        conv_silu_k<<<(SEQ * CONV_DIM) / 256, 256, 0, stream>>>(
            zx, zx1, conv_w + (size_t)l * CONV_DIM * D_CONV, conv_b + (size_t)l * CONV_DIM, xBC);

        dtcum_k<<<dim3(NCHUNKS, NHEADS), 64, 0, stream>>>(
            zx, zx1, dt_bias + (size_t)l * NHEADS, A_log + (size_t)l * NHEADS, dtb, acs);

        cmg_k<<<NCHUNKS, 256, 0, stream>>>(xBC, cm, btg);

        ydst_k<<<dim3(NCHUNKS, NHEADS), 256, 0, stream>>>(cm, btg, xBC, dtb, acs, Y, st);

        rec_k<<<(NHEADS * D_STATE * HEADDIM) / 256, 256, 0, stream>>>(st, acs);

        yoff_k<<<dim3(NCHUNKS, NHEADS), 256, 0, stream>>>(xBC, acs, st, Dp + (size_t)l * NHEADS, Y);

        if (tier <= 1) {
            gatednorm_bf16_k<<<SEQ, 256, 0, stream>>>(Y, zx, zx1, mixer_norm_w + (size_t)l * D_INNER, Yb);
            if (tier == 0) {
                gemm_bt_bf16<64, 128, 4, false><<<dim3(GX_OUT, 2), 256, 0, stream>>>(
                    Yb, wout + (size_t)l * 2097152, o,
                    D_MODEL, 1024, D_INNER, D_INNER, D_MODEL, NT_OUT, SZ_H);
            } else {
                gemm_bt_bf16<64, 128, 4, true><<<dim3(GX_OUT, 1), 256, 0, stream>>>(
                    Yb, wout + (size_t)l * 2097152, h,
                    D_MODEL, 2048, D_INNER, D_INNER, D_MODEL, NT_OUT, 0);
            }
        } else {
            gatednorm_k<<<SEQ, 256, 0, stream>>>(Y, zx, mixer_norm_w + (size_t)l * D_INNER);
            gemm_nt_cvt<true><<<dim3(8, 8), 256, 0, stream>>>(
                Y, out_proj_w + (size_t)l * D_MODEL * D_INNER, h,
                SEQ, D_MODEL, D_INNER, D_INNER, D_INNER, D_MODEL);
        }
    }

    if (tier <= 1) {
        rmsnorm_fold_bf16_k<<<SEQ, 256, 0, stream>>>(
            h, (tier == 0) ? o : nullptr, norm_f_w, ub);
        gemm256n128_d3<<<dim3(GX_LM128), 512, 0, stream>>>(
            ub, embb, out, VOCAB, 1024, D_MODEL, D_MODEL, VOCAB, NT_LM128);
    } else {
        rmsnorm_k<<<SEQ, 256, 0, stream>>>(h, norm_f_w, u);
        gemm_nt_cvt<false><<<dim3(8, (VOCAB + 127) / 128), 256, 0, stream>>>(
            u, emb, out, SEQ, VOCAB, D_MODEL, D_MODEL, D_MODEL, VOCAB);
    }
}

// Round 17
// 689.591 us; speedup vs baseline: 1.0370x; 1.0370x over previous
//
#include <hip/hip_runtime.h>
#include <hip/hip_bf16.h>
#include <math.h>

#define D_MODEL   1024
#define VOCAB     50288
#define D_STATE   128
#define D_CONV    4
#define HEADDIM   64
#define CHUNK     64
#define D_INNER   2048
#define NHEADS    32
#define D_IN_PROJ 4384
#define CONV_DIM  2304
#define SEQ       1024
#define NCHUNKS   16
#define EPS       1e-5f
#define SZH       1048576   // SEQ*D_MODEL

typedef __bf16 bf16x8 __attribute__((ext_vector_type(8)));
typedef __bf16 bf16x4 __attribute__((ext_vector_type(4)));
typedef float  f32x4  __attribute__((ext_vector_type(4)));

// ---------------------------------------------------------------- utilities
__device__ __forceinline__ float blockReduceSum256(float v, float* sm) {
    #pragma unroll
    for (int off = 32; off > 0; off >>= 1) v += __shfl_down(v, off);
    if ((threadIdx.x & 63) == 0) sm[threadIdx.x >> 6] = v;
    __syncthreads();
    return sm[0] + sm[1] + sm[2] + sm[3];
}

__device__ __forceinline__ float sigmoidf_(float x) { return 1.0f / (1.0f + expf(-x)); }

__device__ __forceinline__ void gload_lds16(const __bf16* g, __bf16* l) {
    __builtin_amdgcn_global_load_lds(
        (const __attribute__((address_space(1))) void*)g,
        (__attribute__((address_space(3))) void*)l,
        16, 0, 0);
}

// ---------------------------------------------------------------- f32 -> bf16 bulk convert
__global__ void cvt_bf16_k(const float* __restrict__ src, __bf16* __restrict__ dst, long n) {
    long i = ((long)blockIdx.x * 256 + threadIdx.x) * 8;
    long stride = (long)gridDim.x * 256 * 8;
    for (; i < n; i += stride) {
        float4 a = *(const float4*)(src + i);
        float4 b = *(const float4*)(src + i + 4);
        bf16x8 o;
        o[0] = (__bf16)a.x; o[1] = (__bf16)a.y; o[2] = (__bf16)a.z; o[3] = (__bf16)a.w;
        o[4] = (__bf16)b.x; o[5] = (__bf16)b.y; o[6] = (__bf16)b.z; o[7] = (__bf16)b.w;
        *(bf16x8*)(dst + i) = o;
    }
}

// ---------------------------------------------------------------- embedding gather
__global__ void gather_k(const int* __restrict__ ids, const float* __restrict__ emb,
                         float* __restrict__ h) {
    int s = blockIdx.x;
    int id = ids[s];
    const float4* src = (const float4*)(emb + (size_t)id * D_MODEL);
    float4* dst = (float4*)(h + (size_t)s * D_MODEL);
    dst[threadIdx.x] = src[threadIdx.x];
}

// ---------------------------------------------------------------- rmsnorm (tier C)
__global__ void rmsnorm_k(const float* __restrict__ x, const float* __restrict__ w,
                          float* __restrict__ o) {
    __shared__ float red[4];
    int s = blockIdx.x, t = threadIdx.x;
    float4 v = ((const float4*)(x + (size_t)s * D_MODEL))[t];
    float ss = v.x*v.x + v.y*v.y + v.z*v.z + v.w*v.w;
    float tot = blockReduceSum256(ss, red);
    float r = rsqrtf(tot / (float)D_MODEL + EPS);
    float4 wv = ((const float4*)w)[t];
    float4 ov;
    ov.x = v.x * r * wv.x; ov.y = v.y * r * wv.y;
    ov.z = v.z * r * wv.z; ov.w = v.w * r * wv.w;
    ((float4*)(o + (size_t)s * D_MODEL))[t] = ov;
}

// ---------------------------------------------------------------- fold 4 partials + rmsnorm -> bf16
__global__ void rmsnorm_fold_bf16_k(float* __restrict__ h, const float* __restrict__ o,
                                    const float* __restrict__ w, __bf16* __restrict__ out) {
    __shared__ float red[4];
    int s = blockIdx.x, t = threadIdx.x;
    float4 v = ((const float4*)(h + (size_t)s * D_MODEL))[t];
    if (o) {
        #pragma unroll
        for (int j = 0; j < 4; ++j) {
            float4 ov = ((const float4*)(o + (size_t)j * SZH + (size_t)s * D_MODEL))[t];
            v.x += ov.x; v.y += ov.y; v.z += ov.z; v.w += ov.w;
        }
        ((float4*)(h + (size_t)s * D_MODEL))[t] = v;
    }
    float ss = v.x*v.x + v.y*v.y + v.z*v.z + v.w*v.w;
    float tot = blockReduceSum256(ss, red);
    float r = rsqrtf(tot / (float)D_MODEL + EPS);
    float4 wv = ((const float4*)w)[t];
    bf16x4 ov;
    ov[0] = (__bf16)(v.x * r * wv.x); ov[1] = (__bf16)(v.y * r * wv.y);
    ov[2] = (__bf16)(v.z * r * wv.z); ov[3] = (__bf16)(v.w * r * wv.w);
    *(bf16x4*)(out + (size_t)s * D_MODEL + t * 4) = ov;
}

// ---------------------------------------------------------------- gated rmsnorm (tier C)
__global__ void gatednorm_k(float* __restrict__ Y, const float* __restrict__ zx,
                            const float* __restrict__ w) {
    __shared__ float red[4];
    int s = blockIdx.x, t = threadIdx.x;
    float4 y0 = ((const float4*)(Y + (size_t)s * D_INNER))[2*t];
    float4 y1 = ((const float4*)(Y + (size_t)s * D_INNER))[2*t+1];
    float4 z0 = ((const float4*)(zx + (size_t)s * D_IN_PROJ))[2*t];
    float4 z1 = ((const float4*)(zx + (size_t)s * D_IN_PROJ))[2*t+1];
    float g[8];
    float yv[8] = { y0.x,y0.y,y0.z,y0.w, y1.x,y1.y,y1.z,y1.w };
    float zv[8] = { z0.x,z0.y,z0.z,z0.w, z1.x,z1.y,z1.z,z1.w };
    float ss = 0.f;
    #pragma unroll
    for (int j = 0; j < 8; ++j) {
        float gg = yv[j] * zv[j] * sigmoidf_(zv[j]);
        g[j] = gg;
        ss += gg * gg;
    }
    float tot = blockReduceSum256(ss, red);
    float r = rsqrtf(tot / (float)D_INNER + EPS);
    float4 o0, o1;
    o0.x = g[0]*r*w[8*t+0]; o0.y = g[1]*r*w[8*t+1]; o0.z = g[2]*r*w[8*t+2]; o0.w = g[3]*r*w[8*t+3];
    o1.x = g[4]*r*w[8*t+4]; o1.y = g[5]*r*w[8*t+5]; o1.z = g[6]*r*w[8*t+6]; o1.w = g[7]*r*w[8*t+7];
    ((float4*)(Y + (size_t)s * D_INNER))[2*t]   = o0;
    ((float4*)(Y + (size_t)s * D_INNER))[2*t+1] = o1;
}

// ---------------------------------------------------------------- gated rmsnorm -> bf16
__global__ void gatednorm_bf16_k(const float* __restrict__ Y, const float* __restrict__ zx0,
                                 const float* __restrict__ zx1,
                                 const float* __restrict__ w, __bf16* __restrict__ o) {
    __shared__ float red[4];
    int s = blockIdx.x, t = threadIdx.x;
    float4 y0 = ((const float4*)(Y + (size_t)s * D_INNER))[2*t];
    float4 y1 = ((const float4*)(Y + (size_t)s * D_INNER))[2*t+1];
    float4 z0 = ((const float4*)(zx0 + (size_t)s * D_IN_PROJ))[2*t];
    float4 z1 = ((const float4*)(zx0 + (size_t)s * D_IN_PROJ))[2*t+1];
    if (zx1) {
        float4 a0 = ((const float4*)(zx1 + (size_t)s * D_IN_PROJ))[2*t];
        float4 a1 = ((const float4*)(zx1 + (size_t)s * D_IN_PROJ))[2*t+1];
        z0.x += a0.x; z0.y += a0.y; z0.z += a0.z; z0.w += a0.w;
        z1.x += a1.x; z1.y += a1.y; z1.z += a1.z; z1.w += a1.w;
    }
    float g[8];
    float yv[8] = { y0.x,y0.y,y0.z,y0.w, y1.x,y1.y,y1.z,y1.w };
    float zv[8] = { z0.x,z0.y,z0.z,z0.w, z1.x,z1.y,z1.z,z1.w };
    float ss = 0.f;
    #pragma unroll
    for (int j = 0; j < 8; ++j) {
        float gg = yv[j] * zv[j] * sigmoidf_(zv[j]);
        g[j] = gg;
        ss += gg * gg;
    }
    float tot = blockReduceSum256(ss, red);
    float r = rsqrtf(tot / (float)D_INNER + EPS);
    bf16x8 ov;
    #pragma unroll
    for (int j = 0; j < 8; ++j) ov[j] = (__bf16)(g[j] * r * w[8*t+j]);
    *(bf16x8*)(o + (size_t)s * D_INNER + t * 8) = ov;
}

// ---------------------------------------------------------------- 256x128 deep-interleaved GEMM (BT), 3-buffer ring (best):
// BK=32, 3x24KB LDS (72KB -> 2 blocks/CU), prefetch 2 ahead, 2 phases/iter
// {stage || ds_read || 8 MFMA}, FIFO vmcnt(5/3/0), 2-way-free swizzle, setprio, XCD remap.
__global__ __launch_bounds__(512) void gemm256n128_d3(const __bf16* __restrict__ A,
                                                      const __bf16* __restrict__ B,
                                                      float* __restrict__ C,
                                                      int N, int K,
                                                      int lda, int ldb, int ldc,
                                                      int ntiles) {
    __shared__ __bf16 lds[3 * 12288];   // buf: A[256][32] @0 (8192 el), B[128][32] @8192 (4096 el)

    const int d = blockIdx.x;
    const int xcd = d & 7, kk = d >> 3;
    const int m_tile = kk & 3, p = kk >> 2;        // 4 M-tiles (M=1024)
    const int n_tile = xcd + (p << 3);
    if (n_tile >= ntiles) return;
    const int bm0 = m_tile * 256, bn0 = n_tile * 128;

    const int tid = threadIdx.x;
    const int l = tid & 63, w = tid >> 6;
    const int wr = w >> 2, wc = w & 3;             // 2x4 wave grid; wave owns 128x32
    const int lrow = l & 15;
    const int khi = l >> 4;
    const int kb = ((khi ^ ((lrow >> 1) & 3)) << 3);
    const int Lr = l >> 2;                          // row within 16-row chunk
    const int sblk = (((l & 3) ^ ((Lr >> 1) & 3)) << 3);

    int aoff[8], boff[2];
    #pragma unroll
    for (int m = 0; m < 8; ++m) aoff[m] = (wr * 128 + m * 16 + lrow) * 32;
    #pragma unroll
    for (int n = 0; n < 2; ++n) boff[n] = 8192 + (wc * 32 + n * 16 + lrow) * 32;

    f32x4 acc[8][2];
    #pragma unroll
    for (int m = 0; m < 8; ++m)
        #pragma unroll
        for (int n = 0; n < 2; ++n) acc[m][n] = (f32x4){0.f,0.f,0.f,0.f};

    auto stage_a = [&](int kt, __bf16* dst) {
        #pragma unroll
        for (int r = 0; r < 2; ++r) {
            int chunk = r * 8 + w;
            int grow = bm0 + chunk * 16 + Lr;
            const __bf16* g = A + (size_t)grow * lda + kt * 32 + sblk;
            gload_lds16(g, dst + chunk * 512);
        }
    };
    auto stage_b = [&](int kt, __bf16* dst) {
        int grow = bn0 + w * 16 + Lr;
        if (grow > N - 1) grow = N - 1;
        const __bf16* g = B + (size_t)grow * ldb + kt * 32 + sblk;
        gload_lds16(g, dst + w * 512);
    };

    // prologue: tiles 0,1 in flight (6 loads/thread)
    stage_a(0, lds);          stage_b(0, lds + 8192);
    stage_a(1, lds + 12288);  stage_b(1, lds + 12288 + 8192);

    const int nt = K / 32;   // 32
    for (int t = 0; t < nt; ++t) {
        __bf16* bb = lds + (t % 3) * 12288;
        __bf16* nb = lds + ((t + 2) % 3) * 12288;
        bf16x8 af[4], bfv[2];

        if (t + 2 < nt) {
            stage_a(t + 2, nb);
            asm volatile("s_waitcnt vmcnt(5)" ::: "memory");  // t+1(3) + A(t+2)(2) remain
        } else if (t + 1 < nt) {
            asm volatile("s_waitcnt vmcnt(3)" ::: "memory");
        } else {
            asm volatile("s_waitcnt vmcnt(0)" ::: "memory");
        }
        __builtin_amdgcn_s_barrier();
        #pragma unroll
        for (int m = 0; m < 4; ++m) af[m] = *(const bf16x8*)&bb[aoff[m] + kb];
        #pragma unroll
        for (int n = 0; n < 2; ++n) bfv[n] = *(const bf16x8*)&bb[boff[n] + kb];
        __builtin_amdgcn_s_setprio(1);
        #pragma unroll
        for (int m = 0; m < 4; ++m)
            #pragma unroll
            for (int n = 0; n < 2; ++n)
                acc[m][n] = __builtin_amdgcn_mfma_f32_16x16x32_bf16(af[m], bfv[n], acc[m][n], 0, 0, 0);
        __builtin_amdgcn_s_setprio(0);
        __builtin_amdgcn_s_barrier();

        if (t + 2 < nt) stage_b(t + 2, nb + 8192);
        #pragma unroll
        for (int m = 0; m < 4; ++m) af[m] = *(const bf16x8*)&bb[aoff[m + 4] + kb];
        __builtin_amdgcn_s_setprio(1);
        #pragma unroll
        for (int m = 0; m < 4; ++m)
            #pragma unroll
            for (int n = 0; n < 2; ++n)
                acc[m + 4][n] = __builtin_amdgcn_mfma_f32_16x16x32_bf16(af[m], bfv[n], acc[m + 4][n], 0, 0, 0);
        __builtin_amdgcn_s_setprio(0);
        __builtin_amdgcn_s_barrier();
    }

    // epilogue: C/D layout col = l&15, row = (l>>4)*4 + reg
    const int r0q = (l >> 4) * 4;
    #pragma unroll
    for (int m = 0; m < 8; ++m) {
        int gr = bm0 + wr * 128 + m * 16 + r0q;
        #pragma unroll
        for (int n = 0; n < 2; ++n) {
            int gc = bn0 + wc * 32 + n * 16 + lrow;
            if (gc < N) {
                #pragma unroll
                for (int rr = 0; rr < 4; ++rr)
                    C[(size_t)(gr + rr) * ldc + gc] = acc[m][n][rr];
            }
        }
    }
}

// ---------------------------------------------------------------- bf16 MFMA GEMM (BT), XCD-affinity + split-K (in/out_proj)
template<int TM, int TN, int MTL2, bool ACC>
__global__ __launch_bounds__(256) void gemm_bt_bf16(const __bf16* __restrict__ A,
                                                    const __bf16* __restrict__ B,
                                                    float* __restrict__ C,
                                                    int N, int klen,
                                                    int lda, int ldb, int ldc,
                                                    int ntiles, size_t csplit) {
    constexpr int FM = TM / 32;
    constexpr int FN = TN / 32;
    __shared__ __bf16 As[TM * 32];
    __shared__ __bf16 Bs[TN * 32];

    const int d = blockIdx.x;
    const int xcd = d & 7;
    const int kk = d >> 3;
    const int p = kk >> MTL2;
    const int m_tile = kk & ((1 << MTL2) - 1);
    const int n_tile = xcd + (p << 3);
    if (n_tile >= ntiles) return;

    const int k_begin = blockIdx.y * klen;
    C += (size_t)blockIdx.y * csplit;

    const int bm0 = m_tile * TM;
    const int bn0 = n_tile * TN;
    const int t = threadIdx.x;
    const int l = t & 63;
    const int w = t >> 6;
    const int wr = w >> 1, wc = w & 1;
    const int lrow = l & 15;
    const int lk   = (l >> 4) * 8;
    const int srow = l >> 2;
    const int scol = (l & 3) * 8;

    f32x4 acc[FM][FN];
    #pragma unroll
    for (int m = 0; m < FM; ++m)
        #pragma unroll
        for (int n = 0; n < FN; ++n)
            acc[m][n] = (f32x4){0.f, 0.f, 0.f, 0.f};

    for (int k0 = k_begin; k0 < k_begin + klen; k0 += 32) {
        __syncthreads();
        #pragma unroll
        for (int i = 0; i < TM / 64; ++i) {
            int r0 = w * (TM / 4) + i * 16;
            const __bf16* g = A + (size_t)(bm0 + r0 + srow) * lda + k0 + scol;
            gload_lds16(g, As + (size_t)r0 * 32);
        }
        #pragma unroll
        for (int i = 0; i < TN / 64; ++i) {
            int r0 = w * (TN / 4) + i * 16;
            int gn = bn0 + r0 + srow; if (gn > N - 1) gn = N - 1;
            const __bf16* g = B + (size_t)gn * ldb + k0 + scol;
            gload_lds16(g, Bs + (size_t)r0 * 32);
        }
        __syncthreads();

        bf16x8 af[FM], bfr[FN];
        #pragma unroll
        for (int m = 0; m < FM; ++m)
            af[m] = *(const bf16x8*)&As[(wr * (TM/2) + m * 16 + lrow) * 32 + lk];
        #pragma unroll
        for (int n = 0; n < FN; ++n)
            bfr[n] = *(const bf16x8*)&Bs[(wc * (TN/2) + n * 16 + lrow) * 32 + lk];
        #pragma unroll
        for (int m = 0; m < FM; ++m)
            #pragma unroll
            for (int n = 0; n < FN; ++n)
                acc[m][n] = __builtin_amdgcn_mfma_f32_16x16x32_bf16(af[m], bfr[n], acc[m][n], 0, 0, 0);
    }

    const int r0 = (l >> 4) * 4;
    #pragma unroll
    for (int m = 0; m < FM; ++m) {
        #pragma unroll
        for (int rr = 0; rr < 4; ++rr) {
            int gr = bm0 + wr * (TM/2) + m * 16 + r0 + rr;
            #pragma unroll
            for (int n = 0; n < FN; ++n) {
                int gc = bn0 + wc * (TN/2) + n * 16 + lrow;
                if (gc < N) {
                    size_t off = (size_t)gr * ldc + gc;
                    if (ACC) C[off] += acc[m][n][rr];
                    else     C[off]  = acc[m][n][rr];
                }
            }
        }
    }
}

// ---------------------------------------------------------------- f32-input cvt GEMM (fallback tier)
template<bool ACC>
__global__ __launch_bounds__(256) void gemm_nt_cvt(const float* __restrict__ A,
                                                   const float* __restrict__ B,
                                                   float* __restrict__ C,
                                                   int M, int N, int K,
                                                   int lda, int ldb, int ldc) {
    __shared__ __bf16 As[128][40];
    __shared__ __bf16 Bs[128][40];
    const int bm0 = blockIdx.x * 128;
    const int bn0 = blockIdx.y * 128;
    const int t = threadIdx.x;
    const int l = t & 63;
    const int w = t >> 6;
    const int wr = w >> 1;
    const int wc = w & 1;
    const int lrow = l & 15;
    const int lk   = (l >> 4) * 8;

    f32x4 acc[4][4];
    #pragma unroll
    for (int m = 0; m < 4; ++m)
        #pragma unroll
        for (int n = 0; n < 4; ++n)
            acc[m][n] = (f32x4){0.f, 0.f, 0.f, 0.f};

    for (int k0 = 0; k0 < K; k0 += 32) {
        __syncthreads();
        float4 av[4], bv[4];
        #pragma unroll
        for (int i = 0; i < 4; ++i) {
            int idx = t + i * 256;
            int r = idx >> 3;
            int c4 = (idx & 7) * 4;
            av[i] = *(const float4*)(A + (size_t)(bm0 + r) * lda + k0 + c4);
            int gn = bn0 + r; if (gn > N - 1) gn = N - 1;
            bv[i] = *(const float4*)(B + (size_t)gn * ldb + k0 + c4);
        }
        #pragma unroll
        for (int i = 0; i < 4; ++i) {
            int idx = t + i * 256;
            int r = idx >> 3;
            int c4 = (idx & 7) * 4;
            bf16x4 aw, bw;
            aw[0] = (__bf16)av[i].x; aw[1] = (__bf16)av[i].y;
            aw[2] = (__bf16)av[i].z; aw[3] = (__bf16)av[i].w;
            bw[0] = (__bf16)bv[i].x; bw[1] = (__bf16)bv[i].y;
            bw[2] = (__bf16)bv[i].z; bw[3] = (__bf16)bv[i].w;
            *(bf16x4*)&As[r][c4] = aw;
            *(bf16x4*)&Bs[r][c4] = bw;
        }
        __syncthreads();

        bf16x8 af[4], bfr[4];
        #pragma unroll
        for (int m = 0; m < 4; ++m)
            af[m] = *(const bf16x8*)&As[wr * 64 + m * 16 + lrow][lk];
        #pragma unroll
        for (int n = 0; n < 4; ++n)
            bfr[n] = *(const bf16x8*)&Bs[wc * 64 + n * 16 + lrow][lk];
        #pragma unroll
        for (int m = 0; m < 4; ++m)
            #pragma unroll
            for (int n = 0; n < 4; ++n)
                acc[m][n] = __builtin_amdgcn_mfma_f32_16x16x32_bf16(af[m], bfr[n], acc[m][n], 0, 0, 0);
    }

    const int r0 = (l >> 4) * 4;
    #pragma unroll
    for (int m = 0; m < 4; ++m) {
        #pragma unroll
        for (int rr = 0; rr < 4; ++rr) {
            int gr = bm0 + wr * 64 + m * 16 + r0 + rr;
            #pragma unroll
            for (int n = 0; n < 4; ++n) {
                int gc = bn0 + wc * 64 + n * 16 + lrow;
                if (gc < N) {
                    size_t off = (size_t)gr * ldc + gc;
                    if (ACC) C[off] += acc[m][n][rr];
                    else     C[off]  = acc[m][n][rr];
                }
            }
        }
    }
}

// ---------------------------------------------------------------- causal depthwise conv + silu
__global__ void conv_silu_k(const float* __restrict__ zx0, const float* __restrict__ zx1,
                            const float* __restrict__ w,
                            const float* __restrict__ b, float* __restrict__ xBC) {
    int idx = blockIdx.x * 256 + threadIdx.x;
    if (idx >= SEQ * CONV_DIM) return;
    int s = idx / CONV_DIM, c = idx - s * CONV_DIM;
    float acc = b[c];
    #pragma unroll
    for (int k = 0; k < D_CONV; ++k) {
        int si = s + k - (D_CONV - 1);
        if (si >= 0) {
            size_t o = (size_t)si * D_IN_PROJ + D_INNER + c;
            float v = zx0[o];
            if (zx1) v += zx1[o];
            acc = fmaf(v, w[c * D_CONV + k], acc);
        }
    }
    xBC[idx] = acc * sigmoidf_(acc);
}

// ---------------------------------------------------------------- fused dt=softplus + per-chunk cumsum
__global__ void dtcum_k(const float* __restrict__ zx0, const float* __restrict__ zx1,
                        const float* __restrict__ dt_bias,
                        const float* __restrict__ A_log,
                        float* __restrict__ dtb, float* __restrict__ acs) {
    int c = blockIdx.x, h = blockIdx.y, l = threadIdx.x; // 64 threads
    int s = c * 64 + l;
    size_t o = (size_t)s * D_IN_PROJ + (D_IN_PROJ - NHEADS) + h;
    float v = zx0[o];
    if (zx1) v += zx1[o];
    v += dt_bias[h];
    float dt = (v > 20.f) ? v : log1pf(expf(v));
    dtb[(size_t)s * NHEADS + h] = dt;
    float a = -expf(A_log[h]);
    float x = a * dt;
    #pragma unroll
    for (int off = 1; off < 64; off <<= 1) {
        float oo = __shfl_up(x, off);
        if (l >= off) x += oo;
    }
    acs[(size_t)h * SEQ + s] = x;
}

// ---------------------------------------------------------------- MFMA: CM[c] = C·B^T + Btg (B transposed, bf16)
__global__ __launch_bounds__(256) void cmg_k(const float* __restrict__ xBC,
                                             float* __restrict__ cm,
                                             __bf16* __restrict__ btg) {
    const int c = blockIdx.x;
    const int LDP = 136;
    __shared__ __bf16 Cs[64 * 136];
    __shared__ __bf16 Bs[64 * 136];
    const int t = threadIdx.x;
    const int l = t & 63;
    const int w = t >> 6;

    #pragma unroll
    for (int i = 0; i < 8; ++i) {
        int e = t + i * 256;
        int row = e >> 5, n4 = (e & 31) * 4;
        float4 vc = *(const float4*)(xBC + (size_t)(c*64 + row) * CONV_DIM + D_INNER + D_STATE + n4);
        float4 vb = *(const float4*)(xBC + (size_t)(c*64 + row) * CONV_DIM + D_INNER + n4);
        bf16x4 cc, bb;
        cc[0] = (__bf16)vc.x; cc[1] = (__bf16)vc.y; cc[2] = (__bf16)vc.z; cc[3] = (__bf16)vc.w;
        bb[0] = (__bf16)vb.x; bb[1] = (__bf16)vb.y; bb[2] = (__bf16)vb.z; bb[3] = (__bf16)vb.w;
        *(bf16x4*)&Cs[row * LDP + n4] = cc;
        *(bf16x4*)&Bs[row * LDP + n4] = bb;
    }
    __syncthreads();

    #pragma unroll
    for (int i = 0; i < 4; ++i) {
        int e8 = t + i * 256;
        int n = e8 >> 3, l8 = (e8 & 7) * 8;
        bf16x8 o;
        #pragma unroll
        for (int j = 0; j < 8; ++j) o[j] = Bs[(l8 + j) * LDP + n];
        *(bf16x8*)(btg + ((size_t)c * 128 + n) * 64 + l8) = o;
    }

    const int lrow = l & 15;
    const int lk   = (l >> 4) * 8;
    const int l0 = w * 16;
    f32x4 acc[4];
    #pragma unroll
    for (int n = 0; n < 4; ++n) acc[n] = (f32x4){0.f,0.f,0.f,0.f};
    #pragma unroll
    for (int kc = 0; kc < 4; ++kc) {
        bf16x8 a = *(const bf16x8*)&Cs[(l0 + lrow) * LDP + kc * 32 + lk];
        #pragma unroll
        for (int n = 0; n < 4; ++n) {
            bf16x8 b = *(const bf16x8*)&Bs[(n * 16 + lrow) * LDP + kc * 32 + lk];
            acc[n] = __builtin_amdgcn_mfma_f32_16x16x32_bf16(a, b, acc[n], 0, 0, 0);
        }
    }
    const int r0 = (l >> 4) * 4;
    #pragma unroll
    for (int n = 0; n < 4; ++n)
        #pragma unroll
        for (int r = 0; r < 4; ++r)
            cm[(size_t)c * 4096 + (l0 + r0 + r) * 64 + n * 16 + lrow] = acc[n][r];
}

// ---------------------------------------------------------------- MFMA fused Y_diag + states, per (c,h)
__global__ __launch_bounds__(256) void ydst_k(const float* __restrict__ cm,
                                              const __bf16* __restrict__ btg,
                                              const float* __restrict__ xBC,
                                              const float* __restrict__ dtb,
                                              const float* __restrict__ acs,
                                              float* __restrict__ Y,
                                              float* __restrict__ st) {
    const int c = blockIdx.x, h = blockIdx.y;
    const int LDP = 72;
    __shared__ __bf16 Xt[64 * 72];
    __shared__ __bf16 X2[64 * 72];
    __shared__ __bf16 G [64 * 72];
    __shared__ __bf16 Bt[128 * 72];
    __shared__ float arow[64];
    __shared__ float decl[64];
    const int t = threadIdx.x;
    const int l = t & 63;
    const int w = t >> 6;

    if (t < 64) arow[t] = acs[(size_t)h * SEQ + c * 64 + t];
    __syncthreads();
    const float alast = arow[63];
    if (t < 64) decl[t] = expf(alast - arow[t]);
    #pragma unroll
    for (int i = 0; i < 16; ++i) {
        int e = t + i * 256;
        int gl = e >> 6, sx = e & 63;
        G[gl * LDP + sx] = (sx <= gl) ? (__bf16)(cm[(size_t)c * 4096 + e] * expf(arow[gl] - arow[sx])) : (__bf16)0.f;
    }
    #pragma unroll
    for (int i = 0; i < 4; ++i) {
        int e8 = t + i * 256;
        int n = e8 >> 3, l8 = (e8 & 7) * 8;
        *(bf16x8*)&Bt[n * LDP + l8] = *(const bf16x8*)(btg + ((size_t)c * 128 + n) * 64 + l8);
    }
    __syncthreads();
    #pragma unroll
    for (int i = 0; i < 4; ++i) {
        int e4 = t + i * 256;
        int sx = e4 >> 4, p4 = (e4 & 15) * 4;
        int s = c * 64 + sx;
        float4 v = *(const float4*)(xBC + (size_t)s * CONV_DIM + h * HEADDIM + p4);
        float d = dtb[(size_t)s * NHEADS + h];
        float d2 = d * decl[sx];
        Xt[(p4+0) * LDP + sx] = (__bf16)(v.x * d);
        Xt[(p4+1) * LDP + sx] = (__bf16)(v.y * d);
        Xt[(p4+2) * LDP + sx] = (__bf16)(v.z * d);
        Xt[(p4+3) * LDP + sx] = (__bf16)(v.w * d);
        X2[(p4+0) * LDP + sx] = (__bf16)(v.x * d2);
        X2[(p4+1) * LDP + sx] = (__bf16)(v.y * d2);
        X2[(p4+2) * LDP + sx] = (__bf16)(v.z * d2);
        X2[(p4+3) * LDP + sx] = (__bf16)(v.w * d2);
    }
    __syncthreads();

    const int lrow = l & 15;
    const int lk   = (l >> 4) * 8;
    const int p0 = w * 16;
    const int r0 = (l >> 4) * 4;

    f32x4 acc1[4];
    #pragma unroll
    for (int n = 0; n < 4; ++n) acc1[n] = (f32x4){0.f,0.f,0.f,0.f};
    #pragma unroll
    for (int kc = 0; kc < 2; ++kc) {
        bf16x8 a = *(const bf16x8*)&Xt[(p0 + lrow) * LDP + kc * 32 + lk];
        #pragma unroll
        for (int n = 0; n < 4; ++n) {
            bf16x8 b = *(const bf16x8*)&G[(n * 16 + lrow) * LDP + kc * 32 + lk];
            acc1[n] = __builtin_amdgcn_mfma_f32_16x16x32_bf16(a, b, acc1[n], 0, 0, 0);
        }
    }
    #pragma unroll
    for (int n = 0; n < 4; ++n) {
        int lc = n * 16 + lrow;
        float4 ov; ov.x = acc1[n][0]; ov.y = acc1[n][1]; ov.z = acc1[n][2]; ov.w = acc1[n][3];
        *(float4*)(Y + (size_t)(c*64 + lc) * D_INNER + h * HEADDIM + p0 + r0) = ov;
    }

    f32x4 acc2[8];
    #pragma unroll
    for (int n = 0; n < 8; ++n) acc2[n] = (f32x4){0.f,0.f,0.f,0.f};
    #pragma unroll
    for (int kc = 0; kc < 2; ++kc) {
        bf16x8 a = *(const bf16x8*)&X2[(p0 + lrow) * LDP + kc * 32 + lk];
        #pragma unroll
        for (int n = 0; n < 8; ++n) {
            bf16x8 b = *(const bf16x8*)&Bt[(n * 16 + lrow) * LDP + kc * 32 + lk];
            acc2[n] = __builtin_amdgcn_mfma_f32_16x16x32_bf16(a, b, acc2[n], 0, 0, 0);
        }
    }
    float* stb = st + ((size_t)(c * NHEADS + h) * 64) * 128;
    #pragma unroll
    for (int n = 0; n < 8; ++n) {
        int nc = n * 16 + lrow;
        #pragma unroll
        for (int r = 0; r < 4; ++r)
            stb[(size_t)(p0 + r0 + r) * 128 + nc] = acc2[n][r];
    }
}

// ---------------------------------------------------------------- inter-chunk recurrence
__global__ void rec_k(float* __restrict__ st, const float* __restrict__ acs) {
    int idx = blockIdx.x * 256 + threadIdx.x;
    int h = idx >> 13;
    float S = 0.f;
    for (int c = 0; c < NCHUNKS; ++c) {
        float* p = st + (size_t)c * (NHEADS * D_STATE * HEADDIM) + idx;
        float tmp = *p;
        *p = S;
        float dec = expf(acs[(size_t)h * SEQ + c * 64 + 63]);
        S = fmaf(S, dec, tmp);
    }
}

// ---------------------------------------------------------------- MFMA Y_off + D skip (RMW), per (c,h)
__global__ __launch_bounds__(256) void yoff_k(const float* __restrict__ xBC,
                                              const float* __restrict__ acs,
                                              const float* __restrict__ st,
                                              const float* __restrict__ Dp,
                                              float* __restrict__ Y) {
    const int c = blockIdx.x, h = blockIdx.y;
    const int LDP = 136;
    __shared__ __bf16 Sts[64 * 136];
    __shared__ __bf16 Cs [64 * 136];
    __shared__ float arow[64];
    const int t = threadIdx.x;
    const int l = t & 63;
    const int w = t >> 6;

    if (t < 64) arow[t] = acs[(size_t)h * SEQ + c * 64 + t];
    const float* stb = st + ((size_t)(c * NHEADS + h) * 64) * 128;
    #pragma unroll
    for (int i = 0; i < 8; ++i) {
        int e = t + i * 256;
        int row = e >> 5, n4 = (e & 31) * 4;
        float4 vs = *(const float4*)(stb + (size_t)row * 128 + n4);
        float4 vc = *(const float4*)(xBC + (size_t)(c*64 + row) * CONV_DIM + D_INNER + D_STATE + n4);
        bf16x4 ss, cc;
        ss[0] = (__bf16)vs.x; ss[1] = (__bf16)vs.y; ss[2] = (__bf16)vs.z; ss[3] = (__bf16)vs.w;
        cc[0] = (__bf16)vc.x; cc[1] = (__bf16)vc.y; cc[2] = (__bf16)vc.z; cc[3] = (__bf16)vc.w;
        *(bf16x4*)&Sts[row * LDP + n4] = ss;
        *(bf16x4*)&Cs [row * LDP + n4] = cc;
    }
    __syncthreads();

    const int lrow = l & 15;
    const int lk   = (l >> 4) * 8;
    const int p0 = w * 16;
    const int r0 = (l >> 4) * 4;
    const float dpar = Dp[h];

    f32x4 acc[4];
    #pragma unroll
    for (int n = 0; n < 4; ++n) acc[n] = (f32x4){0.f,0.f,0.f,0.f};
    #pragma unroll
    for (int kc = 0; kc < 4; ++kc) {
        bf16x8 a = *(const bf16x8*)&Sts[(p0 + lrow) * LDP + kc * 32 + lk];
        #pragma unroll
        for (int n = 0; n < 4; ++n) {
            bf16x8 b = *(const bf16x8*)&Cs[(n * 16 + lrow) * LDP + kc * 32 + lk];
            acc[n] = __builtin_amdgcn_mfma_f32_16x16x32_bf16(a, b, acc[n], 0, 0, 0);
        }
    }
    #pragma unroll
    for (int n = 0; n < 4; ++n) {
        int lc = n * 16 + lrow;
        int s = c * 64 + lc;
        float sc = expf(arow[lc]);
        float4 xv = *(const float4*)(xBC + (size_t)s * CONV_DIM + h * HEADDIM + p0 + r0);
        float4 yv = *(float4*)(Y + (size_t)s * D_INNER + h * HEADDIM + p0 + r0);
        yv.x += sc * acc[n][0] + dpar * xv.x;
        yv.y += sc * acc[n][1] + dpar * xv.y;
        yv.z += sc * acc[n][2] + dpar * xv.z;
        yv.w += sc * acc[n][3] + dpar * xv.w;
        *(float4*)(Y + (size_t)s * D_INNER + h * HEADDIM + p0 + r0) = yv;
    }
}

// ---------------------------------------------------------------- host launch
extern "C" void kernel_launch(void* const* d_in, const int* in_sizes, int n_in,
                              void* d_out, int out_size, void* d_ws, size_t ws_size,
                              hipStream_t stream) {
    const int*   ids          = (const int*)d_in[0];
    const float* emb          = (const float*)d_in[1];
    const float* norm_w       = (const float*)d_in[2];
    const float* in_proj_w    = (const float*)d_in[3];
    const float* conv_w       = (const float*)d_in[4];
    const float* conv_b       = (const float*)d_in[5];
    const float* dt_bias      = (const float*)d_in[6];
    const float* A_log        = (const float*)d_in[7];
    const float* Dp           = (const float*)d_in[8];
    const float* mixer_norm_w = (const float*)d_in[9];
    const float* out_proj_w   = (const float*)d_in[10];
    const float* norm_f_w     = (const float*)d_in[11];
    float* out = (float*)d_out;

    const size_t SZ_H = SZH, SZ_U = SZH, SZ_ZX = 4489216, SZ_XBC = 2359296,
                 SZ_DT = 32768, SZ_ACS = 32768, SZ_CM = 65536, SZ_ST = 4194304, SZ_Y = 2097152;
    const size_t SZ_BTG_F = 65536;
    const size_t BF_U = SZ_H, BF_Y = SZ_Y;
    const size_t BF_WIN  = 4ull * 4489216;
    const size_t BF_WOUT = 4ull * 2097152;
    const size_t BF_EMB  = (size_t)VOCAB * D_MODEL;

    const size_t f32_base = SZ_H + SZ_U + SZ_ZX + SZ_XBC + SZ_DT + SZ_ACS + SZ_CM + SZ_BTG_F + SZ_ST + SZ_Y;
    const size_t f32_new  = f32_base + SZ_ZX + 4 * SZ_H;   // zxb + o[4]
    const size_t bf_all   = (BF_U + BF_Y + BF_WIN + BF_WOUT + BF_EMB) * 2;
    const size_t bytesNew = f32_new * 4 + bf_all;
    const size_t bytesOld = f32_base * 4 + bf_all;
    const int tier = (ws_size >= bytesNew) ? 0 : (ws_size >= bytesOld) ? 1 : 2;

    float *h, *u, *dtb, *acs, *cm, *zx, *zxb = nullptr, *xBC, *st, *Y, *o = nullptr;
    __bf16 *btg, *ub = nullptr, *Yb = nullptr, *win = nullptr, *wout = nullptr, *embb = nullptr;

    if (tier <= 1) {
        float* f = (float*)d_ws;
        h = f;   f += SZ_H;
        u = f;   f += SZ_U;
        dtb = f; f += SZ_DT;
        acs = f; f += SZ_ACS;
        cm = f;  f += SZ_CM;
        btg = (__bf16*)f; f += SZ_BTG_F;
        zx = f;  f += SZ_ZX;
        if (tier == 0) {
            zxb = f; f += SZ_ZX;
            o = f;   f += 4 * SZ_H;
        }
        xBC = f; f += SZ_XBC;
        st = f;  f += SZ_ST;
        Y = f;   f += SZ_Y;
        __bf16* bb = (__bf16*)f;
        ub = bb;   bb += BF_U;
        Yb = bb;   bb += BF_Y;
        win = bb;  bb += BF_WIN;
        wout = bb; bb += BF_WOUT;
        embb = bb;
    } else {
        float* f = (float*)d_ws;
        h = f;   f += SZ_H;
        u = f;   f += SZ_U;
        dtb = f; f += SZ_DT;
        acs = f; f += SZ_ACS;
        cm = f;  f += SZ_CM;
        btg = (__bf16*)f; f += SZ_BTG_F;
        float* ob = (float*)d_out;
        zx = ob;
        xBC = zx + SZ_ZX;
        st = xBC + SZ_XBC;
        Y = st + SZ_ST;
    }

    if (tier <= 1) {
        cvt_bf16_k<<<(int)(BF_WIN / 2048), 256, 0, stream>>>(in_proj_w, win, (long)BF_WIN);
        cvt_bf16_k<<<(int)(BF_WOUT / 2048), 256, 0, stream>>>(out_proj_w, wout, (long)BF_WOUT);
        cvt_bf16_k<<<(int)(BF_EMB / 2048), 256, 0, stream>>>(emb, embb, (long)BF_EMB);
    }

    gather_k<<<SEQ, 256, 0, stream>>>(ids, emb, h);

    const int NT_IN  = (D_IN_PROJ + 127) / 128;   // 35
    const int NT_OUT = D_MODEL / 128;             // 8
    const int GX_IN  = 8 * ((NT_IN  + 7) / 8) * 8;   // 320
    const int GX_OUT = 8 * ((NT_OUT + 7) / 8) * 16;  // 128
    const int NT_LM128 = (VOCAB + 127) / 128;     // 393
    const int GX_LM128 = 8 * ((NT_LM128 + 7) / 8) * 4;  // 1600

    for (int l = 0; l < 4; ++l) {
        if (tier <= 1) {
            rmsnorm_fold_bf16_k<<<SEQ, 256, 0, stream>>>(
                h, (tier == 0 && l > 0) ? o : nullptr, norm_w + (size_t)l * D_MODEL, ub);
            if (tier == 0) {
                gemm_bt_bf16<128, 128, 3, false><<<dim3(GX_IN, 2), 256, 0, stream>>>(
                    ub, win + (size_t)l * 4489216, zx,
                    D_IN_PROJ, 512, D_MODEL, D_MODEL, D_IN_PROJ, NT_IN, SZ_ZX);
            } else {
                gemm_bt_bf16<128, 128, 3, false><<<dim3(GX_IN, 1), 256, 0, stream>>>(
                    ub, win + (size_t)l * 4489216, zx,
                    D_IN_PROJ, 1024, D_MODEL, D_MODEL, D_IN_PROJ, NT_IN, 0);
            }
        } else {
            rmsnorm_k<<<SEQ, 256, 0, stream>>>(h, norm_w + (size_t)l * D_MODEL, u);
            gemm_nt_cvt<false><<<dim3(8, 35), 256, 0, stream>>>(
                u, in_proj_w + (size_t)l * D_IN_PROJ * D_MODEL, zx,
                SEQ, D_IN_PROJ, D_MODEL, D_MODEL, D_MODEL, D_IN_PROJ);
        }

        float* zx1 = (tier == 0) ? zxb : nullptr;

        conv_silu_k<<<(SEQ * CONV_DIM) / 256, 256, 0, stream>>>(
            zx, zx1, conv_w + (size_t)l * CONV_DIM * D_CONV, conv_b + (size_t)l * CONV_DIM, xBC);

        dtcum_k<<<dim3(NCHUNKS, NHEADS), 64, 0, stream>>>(
            zx, zx1, dt_bias + (size_t)l * NHEADS, A_log + (size_t)l * NHEADS, dtb, acs);

        cmg_k<<<NCHUNKS, 256, 0, stream>>>(xBC, cm, btg);

        ydst_k<<<dim3(NCHUNKS, NHEADS), 256, 0, stream>>>(cm, btg, xBC, dtb, acs, Y, st);

        rec_k<<<(NHEADS * D_STATE * HEADDIM) / 256, 256, 0, stream>>>(st, acs);

        yoff_k<<<dim3(NCHUNKS, NHEADS), 256, 0, stream>>>(xBC, acs, st, Dp + (size_t)l * NHEADS, Y);

        if (tier <= 1) {
            gatednorm_bf16_k<<<SEQ, 256, 0, stream>>>(Y, zx, zx1, mixer_norm_w + (size_t)l * D_INNER, Yb);
            if (tier == 0) {
                gemm_bt_bf16<64, 128, 4, false><<<dim3(GX_OUT, 4), 256, 0, stream>>>(
                    Yb, wout + (size_t)l * 2097152, o,
                    D_MODEL, 512, D_INNER, D_INNER, D_MODEL, NT_OUT, SZ_H);
            } else {
                gemm_bt_bf16<64, 128, 4, true><<<dim3(GX_OUT, 1), 256, 0, stream>>>(
                    Yb, wout + (size_t)l * 2097152, h,
                    D_MODEL, 2048, D_INNER, D_INNER, D_MODEL, NT_OUT, 0);
            }
        } else {
            gatednorm_k<<<SEQ, 256, 0, stream>>>(Y, zx, mixer_norm_w + (size_t)l * D_INNER);
            gemm_nt_cvt<true><<<dim3(8, 8), 256, 0, stream>>>(
                Y, out_proj_w + (size_t)l * D_MODEL * D_INNER, h,
                SEQ, D_MODEL, D_INNER, D_INNER, D_INNER, D_MODEL);
        }
    }

    if (tier <= 1) {
        rmsnorm_fold_bf16_k<<<SEQ, 256, 0, stream>>>(
            h, (tier == 0) ? o : nullptr, norm_f_w, ub);
        gemm256n128_d3<<<dim3(GX_LM128), 512, 0, stream>>>(
            ub, embb, out, VOCAB, 1024, D_MODEL, D_MODEL, VOCAB, NT_LM128);
    } else {
        rmsnorm_k<<<SEQ, 256, 0, stream>>>(h, norm_f_w, u);
        gemm_nt_cvt<false><<<dim3(8, (VOCAB + 127) / 128), 256, 0, stream>>>(
            u, emb, out, SEQ, VOCAB, D_MODEL, D_MODEL, D_MODEL, VOCAB);
    }
}